// Round 1
// baseline (12.251 us; speedup 1.0000x reference)
//
#include <hip/hip_runtime.h>
#include <math.h>

#define TINY 1e-6f

// One 64-lane wave per ray. N must be 128 (2 samples per lane).
__global__ __launch_bounds__(256) void nerf_render_kernel(
    const float* __restrict__ ray_d,      // [R,3]
    const float* __restrict__ fg_z_max,   // [R]
    const float* __restrict__ z_vals,     // [R,N]
    const float* __restrict__ sigma,      // [R,N]
    const float* __restrict__ rgb,        // [R,N,3]
    const float* __restrict__ bg_rgb,     // [R,3]
    float* __restrict__ o_rgb_map,        // [R,3]
    float* __restrict__ o_weights,        // [R,N]
    float* __restrict__ o_fg_rgb,         // [R,3]
    float* __restrict__ o_depth,          // [R]
    float* __restrict__ o_bg_lambda,      // [R]
    float* __restrict__ o_ldist,          // [R]
    float* __restrict__ o_tv,             // [R]
    int R)
{
    const int N = 128;
    const int lane = threadIdx.x & 63;
    const int wave = threadIdx.x >> 6;
    const int ray  = blockIdx.x * (blockDim.x >> 6) + wave;
    if (ray >= R) return;

    const int s0 = 2 * lane;           // this lane's first sample
    const long base = (long)ray * N + s0;

    // ---- loads (coalesced: 8B/lane for z & sigma, 24B/lane for rgb) ----
    const float2 zz = *reinterpret_cast<const float2*>(z_vals + base);
    const float2 sg = *reinterpret_cast<const float2*>(sigma  + base);
    const float z0 = zz.x, z1 = zz.y;

    const float zmax = fg_z_max[ray];
    const float dxv = ray_d[ray * 3 + 0];
    const float dyv = ray_d[ray * 3 + 1];
    const float dzv = ray_d[ray * 3 + 2];
    const float nrm = sqrtf(dxv * dxv + dyv * dyv + dzv * dzv);

    // z of the sample after s1 = z0 of lane+1 (lane 63: z_max)
    const float znext_raw = __shfl_down(z0, 1);
    const float zb = (lane == 63) ? zmax : znext_raw;

    // interval lengths and midpoints (both scaled by |ray_d|)
    const float d0 = (z1 - z0) * nrm;
    const float d1 = (zb - z1) * nrm;
    const float m0 = 0.5f * (z0 + z1) * nrm;
    const float m1 = 0.5f * (z1 + zb) * nrm;

    // alpha / transmittance factors
    const float e0 = __expf(-sg.x * d0);
    const float e1 = __expf(-sg.y * d1);
    const float a0 = 1.0f - e0;
    const float a1 = 1.0f - e1;
    const float f0 = e0 + TINY;
    const float f1 = e1 + TINY;

    // ---- multiplicative inclusive scan across the wave (pair products) ----
    float x = f0 * f1;
    #pragma unroll
    for (int off = 1; off < 64; off <<= 1) {
        float y = __shfl_up(x, off);
        if (lane >= off) x *= y;
    }
    const float bg_lambda = __shfl(x, 63);           // product of all 128 factors
    float excl = __shfl_up(x, 1);                    // exclusive prefix (pair level)
    if (lane == 0) excl = 1.0f;

    const float T0 = excl;                           // transmittance before s0
    const float T1 = excl * f0;                      // before s1
    const float w0 = a0 * T0;
    const float w1 = a1 * T1;

    // ---- additive exclusive scans for ldist: cum(w), cum(w*m) ----
    const float sw  = w0 + w1;
    const float swm = w0 * m0 + w1 * m1;
    float xs = sw, xm = swm;
    #pragma unroll
    for (int off = 1; off < 64; off <<= 1) {
        float ys = __shfl_up(xs, off);
        float ym = __shfl_up(xm, off);
        if (lane >= off) { xs += ys; xm += ym; }
    }
    const float exw  = xs - sw;    // sum of w over samples < s0
    const float exwm = xm - swm;

    const float cw0 = exw,        cwm0 = exwm;
    const float cw1 = exw + w0,   cwm1 = exwm + w0 * m0;

    float ldist = 2.0f * (w0 * (m0 * cw0 - cwm0) + w1 * (m1 * cw1 - cwm1))
                + (w0 * w0 * d0 + w1 * w1 * d1) * (1.0f / 3.0f);

    // ---- TV: |w[i+1]-w[i]| ----
    const float w0next = __shfl_down(w0, 1);
    float tv = fabsf(w1 - w0) + ((lane < 63) ? fabsf(w0next - w1) : 0.0f);

    // ---- rgb / depth accumulation ----
    const float* rp = rgb + base * 3;
    const float r0 = rp[0], g0 = rp[1], b0 = rp[2];
    const float r1 = rp[3], g1 = rp[4], b1 = rp[5];

    float cr = w0 * r0 + w1 * r1;
    float cg = w0 * g0 + w1 * g1;
    float cb = w0 * b0 + w1 * b1;
    float dep = w0 * z0 + w1 * z1;   // depth uses UNscaled z

    // ---- wave reductions (butterfly) ----
    #pragma unroll
    for (int off = 32; off > 0; off >>= 1) {
        cr    += __shfl_xor(cr, off);
        cg    += __shfl_xor(cg, off);
        cb    += __shfl_xor(cb, off);
        dep   += __shfl_xor(dep, off);
        ldist += __shfl_xor(ldist, off);
        tv    += __shfl_xor(tv, off);
    }

    // ---- stores ----
    *reinterpret_cast<float2*>(o_weights + base) = make_float2(w0, w1);

    if (lane == 0) {
        const float bgr = bg_rgb[ray * 3 + 0];
        const float bgg = bg_rgb[ray * 3 + 1];
        const float bgb = bg_rgb[ray * 3 + 2];
        o_rgb_map[ray * 3 + 0] = cr + bg_lambda * bgr;
        o_rgb_map[ray * 3 + 1] = cg + bg_lambda * bgg;
        o_rgb_map[ray * 3 + 2] = cb + bg_lambda * bgb;
        o_fg_rgb[ray * 3 + 0] = cr;
        o_fg_rgb[ray * 3 + 1] = cg;
        o_fg_rgb[ray * 3 + 2] = cb;
        o_depth[ray]     = dep;
        o_bg_lambda[ray] = bg_lambda;
        o_ldist[ray]     = ldist;
        o_tv[ray]        = tv;
    }
}

extern "C" void kernel_launch(void* const* d_in, const int* in_sizes, int n_in,
                              void* d_out, int out_size, void* d_ws, size_t ws_size,
                              hipStream_t stream) {
    const float* ray_d   = (const float*)d_in[0];
    const float* fg_zmax = (const float*)d_in[1];
    const float* z_vals  = (const float*)d_in[2];
    const float* sigma   = (const float*)d_in[3];
    const float* rgb     = (const float*)d_in[4];
    const float* bg_rgb  = (const float*)d_in[5];

    const int R = in_sizes[1];          // fg_z_max: [R]
    const int N = in_sizes[2] / R;      // fg_z_vals: [R,N]  (must be 128)
    (void)N;

    float* out = (float*)d_out;
    float* o_rgb_map   = out;                       // R*3
    float* o_weights   = o_rgb_map + (long)R * 3;   // R*N
    float* o_fg_rgb    = o_weights + (long)R * 128; // R*3
    float* o_depth     = o_fg_rgb + (long)R * 3;    // R
    float* o_bg_lambda = o_depth + R;               // R
    float* o_ldist     = o_bg_lambda + R;           // R
    float* o_tv        = o_ldist + R;               // R

    const int waves_per_block = 4;                  // 256 threads
    const int grid = (R + waves_per_block - 1) / waves_per_block;
    nerf_render_kernel<<<grid, 256, 0, stream>>>(
        ray_d, fg_zmax, z_vals, sigma, rgb, bg_rgb,
        o_rgb_map, o_weights, o_fg_rgb, o_depth, o_bg_lambda, o_ldist, o_tv, R);
}

// Round 2
// 11.567 us; speedup vs baseline: 1.0591x; 1.0591x over previous
//
#include <hip/hip_runtime.h>
#include <math.h>

#define TINY 1e-6f

// ---- DPP helpers (compile-time ctrl; CDNA/gfx9 DPP set) ----
// ctrl: 0x111..0x118 row_shr:N, 0x130 wave_shl:1, 0x138 wave_shr:1,
//       0x142 row_bcast15, 0x143 row_bcast31
template <int CTRL, int RM, int BM, bool BC>
__device__ __forceinline__ float updpp(float oldv, float x) {
    return __int_as_float(__builtin_amdgcn_update_dpp(
        __float_as_int(oldv), __float_as_int(x), CTRL, RM, BM, BC));
}

// 64-lane inclusive add-scan, 6 VALU ops. Total lands in lane 63.
__device__ __forceinline__ float scan_add(float x) {
    x += updpp<0x111, 0xf, 0xf, true>(0.f, x);   // row_shr:1
    x += updpp<0x112, 0xf, 0xf, true>(0.f, x);   // row_shr:2
    x += updpp<0x114, 0xf, 0xf, true>(0.f, x);   // row_shr:4
    x += updpp<0x118, 0xf, 0xf, true>(0.f, x);   // row_shr:8
    x += updpp<0x142, 0xa, 0xf, true>(0.f, x);   // row_bcast15 -> rows 1,3
    x += updpp<0x143, 0xc, 0xf, true>(0.f, x);   // row_bcast31 -> rows 2,3
    return x;
}

// 64-lane inclusive multiply-scan (identity 1.0 via old + bound_ctrl=0).
__device__ __forceinline__ float scan_mul(float x) {
    x *= updpp<0x111, 0xf, 0xf, false>(1.f, x);
    x *= updpp<0x112, 0xf, 0xf, false>(1.f, x);
    x *= updpp<0x114, 0xf, 0xf, false>(1.f, x);
    x *= updpp<0x118, 0xf, 0xf, false>(1.f, x);
    x *= updpp<0x142, 0xa, 0xf, false>(1.f, x);
    x *= updpp<0x143, 0xc, 0xf, false>(1.f, x);
    return x;
}

// lane i <- lane i-1 across whole wave (lane 0 -> oldv)
__device__ __forceinline__ float wave_shr1(float x, float oldv) {
    return updpp<0x138, 0xf, 0xf, false>(oldv, x);
}
// lane i <- lane i+1 across whole wave (lane 63 -> 0)
__device__ __forceinline__ float wave_shl1(float x) {
    return updpp<0x130, 0xf, 0xf, true>(0.f, x);
}

// One 64-lane wave per ray. N must be 128 (2 samples per lane).
__global__ __launch_bounds__(256) void nerf_render_kernel(
    const float* __restrict__ ray_d,      // [R,3]
    const float* __restrict__ fg_z_max,   // [R]
    const float* __restrict__ z_vals,     // [R,N]
    const float* __restrict__ sigma,      // [R,N]
    const float* __restrict__ rgb,        // [R,N,3]
    const float* __restrict__ bg_rgb,     // [R,3]
    float* __restrict__ o_rgb_map,        // [R,3]
    float* __restrict__ o_weights,        // [R,N]
    float* __restrict__ o_fg_rgb,         // [R,3]
    float* __restrict__ o_depth,          // [R]
    float* __restrict__ o_bg_lambda,      // [R]
    float* __restrict__ o_ldist,          // [R]
    float* __restrict__ o_tv,             // [R]
    int R)
{
    const int lane = threadIdx.x & 63;
    const int wave = threadIdx.x >> 6;
    const int ray  = blockIdx.x * (blockDim.x >> 6) + wave;
    if (ray >= R) return;

    const int base = ray * 128 + 2 * lane;

    // ---- loads (coalesced float2: 8B/lane for z & sigma) ----
    const float2 zz = *reinterpret_cast<const float2*>(z_vals + base);
    const float2 sg = *reinterpret_cast<const float2*>(sigma  + base);
    const float z0 = zz.x, z1 = zz.y;

    // rgb: 24B/lane as 3x float2 (8B aligned)
    const float* rp = rgb + (long)base * 3;
    const float2 r01 = *reinterpret_cast<const float2*>(rp + 0);
    const float2 r23 = *reinterpret_cast<const float2*>(rp + 2);
    const float2 r45 = *reinterpret_cast<const float2*>(rp + 4);

    const float zmax = fg_z_max[ray];
    const float dxv = ray_d[ray * 3 + 0];
    const float dyv = ray_d[ray * 3 + 1];
    const float dzv = ray_d[ray * 3 + 2];
    const float nrm = sqrtf(dxv * dxv + dyv * dyv + dzv * dzv);

    // z of the sample after s1 = z0 of lane+1 (lane 63: z_max)
    const float znext = wave_shl1(z0);
    const float zb = (lane == 63) ? zmax : znext;

    // interval lengths and midpoints (both scaled by |ray_d|)
    const float d0 = (z1 - z0) * nrm;
    const float d1 = (zb - z1) * nrm;
    const float m0 = 0.5f * (z0 + z1) * nrm;
    const float m1 = 0.5f * (z1 + zb) * nrm;

    // alpha / transmittance factors
    const float e0 = __expf(-sg.x * d0);
    const float e1 = __expf(-sg.y * d1);
    const float a0 = 1.0f - e0;
    const float a1 = 1.0f - e1;
    const float f0 = e0 + TINY;
    const float f1 = e1 + TINY;

    // ---- multiplicative inclusive scan (pair products), DPP only ----
    const float x = scan_mul(f0 * f1);     // lane i: prod of factors <= pair i
    const float bg_lambda = x;             // valid in lane 63 (used there only)
    const float excl = wave_shr1(x, 1.0f); // exclusive pair-prefix product

    const float T0 = excl;                 // transmittance before s0
    const float T1 = excl * f0;            // before s1
    const float w0 = a0 * T0;
    const float w1 = a1 * T1;

    // ---- additive inclusive scans for ldist: cum(w), cum(w*m) ----
    const float sw  = w0 + w1;
    const float swm = w0 * m0 + w1 * m1;
    const float xs = scan_add(sw);
    const float xm = scan_add(swm);
    const float exw  = xs - sw;            // sum of w over samples < s0
    const float exwm = xm - swm;

    const float cw0 = exw,       cwm0 = exwm;
    const float cw1 = exw + w0,  cwm1 = exwm + w0 * m0;

    float ldist = 2.0f * (w0 * (m0 * cw0 - cwm0) + w1 * (m1 * cw1 - cwm1))
                + (w0 * w0 * d0 + w1 * w1 * d1) * (1.0f / 3.0f);

    // ---- TV: |w[i+1]-w[i]| ----
    const float w0next = wave_shl1(w0);
    float tv = fabsf(w1 - w0) + ((lane < 63) ? fabsf(w0next - w1) : 0.0f);

    // ---- rgb / depth per-lane partials ----
    float cr = w0 * r01.x + w1 * r23.y;
    float cg = w0 * r01.y + w1 * r45.x;
    float cb = w0 * r23.x + w1 * r45.y;
    float dep = w0 * z0 + w1 * z1;         // depth uses UNscaled z

    // ---- reductions as scans: totals land in lane 63 ----
    cr    = scan_add(cr);
    cg    = scan_add(cg);
    cb    = scan_add(cb);
    dep   = scan_add(dep);
    ldist = scan_add(ldist);
    tv    = scan_add(tv);

    // ---- stores ----
    *reinterpret_cast<float2*>(o_weights + base) = make_float2(w0, w1);

    if (lane == 63) {
        const float bgr = bg_rgb[ray * 3 + 0];
        const float bgg = bg_rgb[ray * 3 + 1];
        const float bgb = bg_rgb[ray * 3 + 2];
        o_rgb_map[ray * 3 + 0] = cr + bg_lambda * bgr;
        o_rgb_map[ray * 3 + 1] = cg + bg_lambda * bgg;
        o_rgb_map[ray * 3 + 2] = cb + bg_lambda * bgb;
        o_fg_rgb[ray * 3 + 0] = cr;
        o_fg_rgb[ray * 3 + 1] = cg;
        o_fg_rgb[ray * 3 + 2] = cb;
        o_depth[ray]     = dep;
        o_bg_lambda[ray] = bg_lambda;
        o_ldist[ray]     = ldist;
        o_tv[ray]        = tv;
    }
}

extern "C" void kernel_launch(void* const* d_in, const int* in_sizes, int n_in,
                              void* d_out, int out_size, void* d_ws, size_t ws_size,
                              hipStream_t stream) {
    const float* ray_d   = (const float*)d_in[0];
    const float* fg_zmax = (const float*)d_in[1];
    const float* z_vals  = (const float*)d_in[2];
    const float* sigma   = (const float*)d_in[3];
    const float* rgb     = (const float*)d_in[4];
    const float* bg_rgb  = (const float*)d_in[5];

    const int R = in_sizes[1];          // fg_z_max: [R]

    float* out = (float*)d_out;
    float* o_rgb_map   = out;                       // R*3
    float* o_weights   = o_rgb_map + (long)R * 3;   // R*N
    float* o_fg_rgb    = o_weights + (long)R * 128; // R*3
    float* o_depth     = o_fg_rgb + (long)R * 3;    // R
    float* o_bg_lambda = o_depth + R;               // R
    float* o_ldist     = o_bg_lambda + R;           // R
    float* o_tv        = o_ldist + R;               // R

    const int waves_per_block = 4;                  // 256 threads
    const int grid = (R + waves_per_block - 1) / waves_per_block;
    nerf_render_kernel<<<grid, 256, 0, stream>>>(
        ray_d, fg_zmax, z_vals, sigma, rgb, bg_rgb,
        o_rgb_map, o_weights, o_fg_rgb, o_depth, o_bg_lambda, o_ldist, o_tv, R);
}

// Round 3
// 11.349 us; speedup vs baseline: 1.0794x; 1.0192x over previous
//
#include <hip/hip_runtime.h>
#include <math.h>

#define TINY 1e-6f

// ---- DPP helpers (compile-time ctrl; CDNA/gfx9 DPP set) ----
template <int CTRL, int RM, int BM, bool BC>
__device__ __forceinline__ float updpp(float oldv, float x) {
    return __int_as_float(__builtin_amdgcn_update_dpp(
        __float_as_int(oldv), __float_as_int(x), CTRL, RM, BM, BC));
}

// 32-lane SEGMENTED inclusive add-scan (independent in lanes 0-31 / 32-63).
// row_shr never crosses 16-lane rows; row_bcast15 with row_mask 0xa only
// feeds lane15->row1 and lane47->row3, so lane31/32 boundary is never crossed.
__device__ __forceinline__ float scan_add32(float x) {
    x += updpp<0x111, 0xf, 0xf, true>(0.f, x);   // row_shr:1
    x += updpp<0x112, 0xf, 0xf, true>(0.f, x);   // row_shr:2
    x += updpp<0x114, 0xf, 0xf, true>(0.f, x);   // row_shr:4
    x += updpp<0x118, 0xf, 0xf, true>(0.f, x);   // row_shr:8
    x += updpp<0x142, 0xa, 0xf, true>(0.f, x);   // row_bcast15 -> rows 1,3
    return x;
}

// 32-lane segmented inclusive multiply-scan (identity via oldv=1, BC=0).
__device__ __forceinline__ float scan_mul32(float x) {
    x *= updpp<0x111, 0xf, 0xf, false>(1.f, x);
    x *= updpp<0x112, 0xf, 0xf, false>(1.f, x);
    x *= updpp<0x114, 0xf, 0xf, false>(1.f, x);
    x *= updpp<0x118, 0xf, 0xf, false>(1.f, x);
    x *= updpp<0x142, 0xa, 0xf, false>(1.f, x);
    return x;
}

// whole-wave lane shifts (cross the 32-boundary; callers mask at boundaries)
__device__ __forceinline__ float wave_shr1(float x, float oldv) {
    return updpp<0x138, 0xf, 0xf, false>(oldv, x);
}
__device__ __forceinline__ float wave_shl1(float x) {
    return updpp<0x130, 0xf, 0xf, true>(0.f, x);
}

// 2 rays per 64-lane wave: lanes 0-31 = ray A, lanes 32-63 = ray B.
// 4 samples per lane (N=128). All bulk loads/stores are aligned dwordx4.
__global__ __launch_bounds__(256) void nerf_render_kernel(
    const float* __restrict__ ray_d,      // [R,3]
    const float* __restrict__ fg_z_max,   // [R]
    const float* __restrict__ z_vals,     // [R,N]
    const float* __restrict__ sigma,      // [R,N]
    const float* __restrict__ rgb,        // [R,N,3]
    const float* __restrict__ bg_rgb,     // [R,3]
    float* __restrict__ o_rgb_map,        // [R,3]
    float* __restrict__ o_weights,        // [R,N]
    float* __restrict__ o_fg_rgb,         // [R,3]
    float* __restrict__ o_depth,          // [R]
    float* __restrict__ o_bg_lambda,      // [R]
    float* __restrict__ o_ldist,          // [R]
    float* __restrict__ o_tv,             // [R]
    int R)
{
    const int lane = threadIdx.x & 63;
    const int wave = threadIdx.x >> 6;
    const int sl   = lane & 31;            // lane within segment
    const int ray  = (blockIdx.x * (blockDim.x >> 6) + wave) * 2 + (lane >> 5);
    if (ray >= R) return;

    const int base = ray * 128 + 4 * sl;   // first sample index of this lane

    // ---- aligned vector loads ----
    const float4 zz = *reinterpret_cast<const float4*>(z_vals + base);   // z0..z3
    const float4 sg = *reinterpret_cast<const float4*>(sigma  + base);
    const float* rp = rgb + (long)base * 3;                              // 48B, 16-aligned
    const float4 v0 = *reinterpret_cast<const float4*>(rp + 0);
    const float4 v1 = *reinterpret_cast<const float4*>(rp + 4);
    const float4 v2 = *reinterpret_cast<const float4*>(rp + 8);

    const float zmax = fg_z_max[ray];
    const float dxv = ray_d[ray * 3 + 0];
    const float dyv = ray_d[ray * 3 + 1];
    const float dzv = ray_d[ray * 3 + 2];
    const float nrm = sqrtf(dxv * dxv + dyv * dyv + dzv * dzv);

    // z after this lane's last sample: next lane's z0; segment-last lane: zmax
    const float znext = wave_shl1(zz.x);
    const float zb = (sl == 31) ? zmax : znext;

    // interval lengths / midpoints (scaled by |ray_d|)
    const float d0 = (zz.y - zz.x) * nrm;
    const float d1 = (zz.z - zz.y) * nrm;
    const float d2 = (zz.w - zz.z) * nrm;
    const float d3 = (zb   - zz.w) * nrm;
    const float m0 = 0.5f * (zz.x + zz.y) * nrm;
    const float m1 = 0.5f * (zz.y + zz.z) * nrm;
    const float m2 = 0.5f * (zz.z + zz.w) * nrm;
    const float m3 = 0.5f * (zz.w + zb  ) * nrm;

    const float e0 = __expf(-sg.x * d0);
    const float e1 = __expf(-sg.y * d1);
    const float e2 = __expf(-sg.z * d2);
    const float e3 = __expf(-sg.w * d3);
    const float f0 = e0 + TINY, f1 = e1 + TINY, f2 = e2 + TINY, f3 = e3 + TINY;

    // ---- segmented multiplicative scan over per-lane quad products ----
    const float quad = (f0 * f1) * (f2 * f3);
    const float xincl = scan_mul32(quad);        // within-segment inclusive
    const float bg_lambda = xincl;               // valid at sl==31
    float excl = wave_shr1(xincl, 1.0f);         // lane32 gets rayA total...
    if (sl == 0) excl = 1.0f;                    // ...masked here

    const float T0 = excl;
    const float T1 = T0 * f0;
    const float T2 = T1 * f1;
    const float T3 = T2 * f2;
    const float w0 = (1.0f - e0) * T0;
    const float w1 = (1.0f - e1) * T1;
    const float w2 = (1.0f - e2) * T2;
    const float w3 = (1.0f - e3) * T3;

    // ---- segmented additive scans for ldist prefixes ----
    const float sw  = ((w0 + w1) + (w2 + w3));
    const float swm = (w0 * m0 + w1 * m1) + (w2 * m2 + w3 * m3);
    const float xs = scan_add32(sw);
    const float xm = scan_add32(swm);
    const float exw  = xs - sw;                  // Σ w over samples before lane
    const float exwm = xm - swm;

    const float cw0 = exw,           cwm0 = exwm;
    const float cw1 = cw0 + w0,      cwm1 = cwm0 + w0 * m0;
    const float cw2 = cw1 + w1,      cwm2 = cwm1 + w1 * m1;
    const float cw3 = cw2 + w2,      cwm3 = cwm2 + w2 * m2;

    float ldist = 2.0f * (w0 * (m0 * cw0 - cwm0) + w1 * (m1 * cw1 - cwm1)
                        + w2 * (m2 * cw2 - cwm2) + w3 * (m3 * cw3 - cwm3))
                + ((w0 * w0 * d0 + w1 * w1 * d1)
                 + (w2 * w2 * d2 + w3 * w3 * d3)) * (1.0f / 3.0f);

    // ---- TV ----
    const float w0next = wave_shl1(w0);          // cross-boundary masked below
    float tv = fabsf(w1 - w0) + fabsf(w2 - w1) + fabsf(w3 - w2)
             + ((sl < 31) ? fabsf(w0next - w3) : 0.0f);

    // ---- rgb / depth partials ----
    // sample rgb: s0=(v0.x,v0.y,v0.z) s1=(v0.w,v1.x,v1.y) s2=(v1.z,v1.w,v2.x) s3=(v2.y,v2.z,v2.w)
    float cr = (w0 * v0.x + w1 * v0.w) + (w2 * v1.z + w3 * v2.y);
    float cg = (w0 * v0.y + w1 * v1.x) + (w2 * v1.w + w3 * v2.z);
    float cb = (w0 * v0.z + w1 * v1.y) + (w2 * v2.x + w3 * v2.w);
    float dep = (w0 * zz.x + w1 * zz.y) + (w2 * zz.z + w3 * zz.w);  // unscaled z

    // ---- segmented reductions (totals land at sl==31 of each segment) ----
    cr    = scan_add32(cr);
    cg    = scan_add32(cg);
    cb    = scan_add32(cb);
    dep   = scan_add32(dep);
    ldist = scan_add32(ldist);
    tv    = scan_add32(tv);

    // ---- stores ----
    *reinterpret_cast<float4*>(o_weights + base) = make_float4(w0, w1, w2, w3);

    if (sl == 31) {
        const float bgr = bg_rgb[ray * 3 + 0];
        const float bgg = bg_rgb[ray * 3 + 1];
        const float bgb = bg_rgb[ray * 3 + 2];
        o_rgb_map[ray * 3 + 0] = cr + bg_lambda * bgr;
        o_rgb_map[ray * 3 + 1] = cg + bg_lambda * bgg;
        o_rgb_map[ray * 3 + 2] = cb + bg_lambda * bgb;
        o_fg_rgb[ray * 3 + 0] = cr;
        o_fg_rgb[ray * 3 + 1] = cg;
        o_fg_rgb[ray * 3 + 2] = cb;
        o_depth[ray]     = dep;
        o_bg_lambda[ray] = bg_lambda;
        o_ldist[ray]     = ldist;
        o_tv[ray]        = tv;
    }
}

extern "C" void kernel_launch(void* const* d_in, const int* in_sizes, int n_in,
                              void* d_out, int out_size, void* d_ws, size_t ws_size,
                              hipStream_t stream) {
    const float* ray_d   = (const float*)d_in[0];
    const float* fg_zmax = (const float*)d_in[1];
    const float* z_vals  = (const float*)d_in[2];
    const float* sigma   = (const float*)d_in[3];
    const float* rgb     = (const float*)d_in[4];
    const float* bg_rgb  = (const float*)d_in[5];

    const int R = in_sizes[1];          // fg_z_max: [R]

    float* out = (float*)d_out;
    float* o_rgb_map   = out;                       // R*3
    float* o_weights   = o_rgb_map + (long)R * 3;   // R*128
    float* o_fg_rgb    = o_weights + (long)R * 128; // R*3
    float* o_depth     = o_fg_rgb + (long)R * 3;    // R
    float* o_bg_lambda = o_depth + R;               // R
    float* o_ldist     = o_bg_lambda + R;           // R
    float* o_tv        = o_ldist + R;               // R

    // 2 rays per wave, 4 waves per block -> 8 rays per block
    const int rays_per_block = 8;
    const int grid = (R + rays_per_block - 1) / rays_per_block;
    nerf_render_kernel<<<grid, 256, 0, stream>>>(
        ray_d, fg_zmax, z_vals, sigma, rgb, bg_rgb,
        o_rgb_map, o_weights, o_fg_rgb, o_depth, o_bg_lambda, o_ldist, o_tv, R);
}

// Round 4
// 9.919 us; speedup vs baseline: 1.2351x; 1.1442x over previous
//
#include <hip/hip_runtime.h>
#include <math.h>

#define TINY 1e-6f

// ---- DPP helpers (compile-time ctrl; CDNA/gfx9 DPP set) ----
template <int CTRL, int RM, int BM, bool BC>
__device__ __forceinline__ float updpp(float oldv, float x) {
    return __int_as_float(__builtin_amdgcn_update_dpp(
        __float_as_int(oldv), __float_as_int(x), CTRL, RM, BM, BC));
}

// 16-lane (row) inclusive add-scan: 4 row-local DPP steps. Total at sl==15.
__device__ __forceinline__ float scan_add16(float x) {
    x += updpp<0x111, 0xf, 0xf, true>(0.f, x);   // row_shr:1
    x += updpp<0x112, 0xf, 0xf, true>(0.f, x);   // row_shr:2
    x += updpp<0x114, 0xf, 0xf, true>(0.f, x);   // row_shr:4
    x += updpp<0x118, 0xf, 0xf, true>(0.f, x);   // row_shr:8
    return x;
}

// 16-lane inclusive multiply-scan (invalid-source lanes keep oldv=1).
__device__ __forceinline__ float scan_mul16(float x) {
    x *= updpp<0x111, 0xf, 0xf, false>(1.f, x);
    x *= updpp<0x112, 0xf, 0xf, false>(1.f, x);
    x *= updpp<0x114, 0xf, 0xf, false>(1.f, x);
    x *= updpp<0x118, 0xf, 0xf, false>(1.f, x);
    return x;
}

// row-local: lane i <- lane i+1 (row-last lane -> 0)
__device__ __forceinline__ float row_shl1(float x) {
    return updpp<0x101, 0xf, 0xf, true>(0.f, x);
}
// row-local: lane i <- lane i-1 (row-first lane -> oldv)
__device__ __forceinline__ float row_shr1(float x, float oldv) {
    return updpp<0x111, 0xf, 0xf, false>(oldv, x);
}

// 4 rays per 64-lane wave (one per 16-lane DPP row), 8 samples per lane.
__global__ __launch_bounds__(256) void nerf_render_kernel(
    const float* __restrict__ ray_d,      // [R,3]
    const float* __restrict__ fg_z_max,   // [R]
    const float* __restrict__ z_vals,     // [R,128]
    const float* __restrict__ sigma,      // [R,128]
    const float* __restrict__ rgb,        // [R,128,3]
    const float* __restrict__ bg_rgb,     // [R,3]
    float* __restrict__ o_rgb_map,        // [R,3]
    float* __restrict__ o_weights,        // [R,128]
    float* __restrict__ o_fg_rgb,         // [R,3]
    float* __restrict__ o_depth,          // [R]
    float* __restrict__ o_bg_lambda,      // [R]
    float* __restrict__ o_ldist,          // [R]
    float* __restrict__ o_tv,             // [R]
    int R)
{
    const int lane = threadIdx.x & 63;
    const int wave = threadIdx.x >> 6;
    const int sl   = lane & 15;            // lane within row/segment
    const int ray  = (blockIdx.x * (blockDim.x >> 6) + wave) * 4 + (lane >> 4);
    if (ray >= R) return;

    const int base = ray * 128 + 8 * sl;   // first of this lane's 8 samples

    // ---- issue ALL loads up front (aligned dwordx4 + uniform scalars) ----
    const float4 za = *reinterpret_cast<const float4*>(z_vals + base);
    const float4 zb4 = *reinterpret_cast<const float4*>(z_vals + base + 4);
    const float4 sa = *reinterpret_cast<const float4*>(sigma + base);
    const float4 sb = *reinterpret_cast<const float4*>(sigma + base + 4);
    const float* rp = rgb + (long)base * 3;                 // 96B, 16-aligned
    const float4 c0 = *reinterpret_cast<const float4*>(rp + 0);
    const float4 c1 = *reinterpret_cast<const float4*>(rp + 4);
    const float4 c2 = *reinterpret_cast<const float4*>(rp + 8);
    const float4 c3 = *reinterpret_cast<const float4*>(rp + 12);
    const float4 c4 = *reinterpret_cast<const float4*>(rp + 16);
    const float4 c5 = *reinterpret_cast<const float4*>(rp + 20);
    const float zmax = fg_z_max[ray];
    const float dxv = ray_d[ray * 3 + 0];
    const float dyv = ray_d[ray * 3 + 1];
    const float dzv = ray_d[ray * 3 + 2];
    const float bgr = bg_rgb[ray * 3 + 0];
    const float bgg = bg_rgb[ray * 3 + 1];
    const float bgb = bg_rgb[ray * 3 + 2];

    const float nrm = sqrtf(dxv * dxv + dyv * dyv + dzv * dzv);

    float z[9];
    z[0] = za.x; z[1] = za.y; z[2] = za.z; z[3] = za.w;
    z[4] = zb4.x; z[5] = zb4.y; z[6] = zb4.z; z[7] = zb4.w;
    const float znext = row_shl1(z[0]);          // next lane's first z
    z[8] = (sl == 15) ? zmax : znext;

    float sig[8];
    sig[0] = sa.x; sig[1] = sa.y; sig[2] = sa.z; sig[3] = sa.w;
    sig[4] = sb.x; sig[5] = sb.y; sig[6] = sb.z; sig[7] = sb.w;

    float col[24];
    col[0]=c0.x; col[1]=c0.y; col[2]=c0.z; col[3]=c0.w;
    col[4]=c1.x; col[5]=c1.y; col[6]=c1.z; col[7]=c1.w;
    col[8]=c2.x; col[9]=c2.y; col[10]=c2.z; col[11]=c2.w;
    col[12]=c3.x; col[13]=c3.y; col[14]=c3.z; col[15]=c3.w;
    col[16]=c4.x; col[17]=c4.y; col[18]=c4.z; col[19]=c4.w;
    col[20]=c5.x; col[21]=c5.y; col[22]=c5.z; col[23]=c5.w;

    float d[8], m[8], e[8], f[8];
    #pragma unroll
    for (int i = 0; i < 8; ++i) {
        d[i] = (z[i + 1] - z[i]) * nrm;
        m[i] = 0.5f * (z[i] + z[i + 1]) * nrm;
        e[i] = __expf(-sig[i] * d[i]);
        f[i] = e[i] + TINY;
    }

    // ---- segmented multiplicative scan over per-lane octet products ----
    const float oct = ((f[0] * f[1]) * (f[2] * f[3])) * ((f[4] * f[5]) * (f[6] * f[7]));
    const float xincl = scan_mul16(oct);
    const float bg_lambda = xincl;               // valid at sl==15
    const float excl = row_shr1(xincl, 1.0f);    // lane sl==0 -> 1.0

    float w[8];
    {
        float T = excl;
        #pragma unroll
        for (int i = 0; i < 8; ++i) {
            w[i] = (1.0f - e[i]) * T;
            T *= f[i];
        }
    }

    // ---- additive scans for ldist prefixes ----
    float sw = 0.f, swm = 0.f;
    #pragma unroll
    for (int i = 0; i < 8; ++i) { sw += w[i]; swm += w[i] * m[i]; }
    const float xs = scan_add16(sw);
    const float xm = scan_add16(swm);

    float cw = xs - sw;                          // Σ w over samples before lane
    float cwm = xm - swm;
    float ld2 = 0.f, ld3 = 0.f;
    #pragma unroll
    for (int i = 0; i < 8; ++i) {
        ld2 += w[i] * (m[i] * cw - cwm);
        ld3 += w[i] * w[i] * d[i];
        cw  += w[i];
        cwm += w[i] * m[i];
    }
    float ldist = 2.0f * ld2 + ld3 * (1.0f / 3.0f);

    // ---- TV ----
    const float w0next = row_shl1(w[0]);
    float tv = 0.f;
    #pragma unroll
    for (int i = 1; i < 8; ++i) tv += fabsf(w[i] - w[i - 1]);
    tv += (sl < 15) ? fabsf(w0next - w[7]) : 0.0f;

    // ---- rgb / depth partials ----
    float cr = 0.f, cg = 0.f, cb = 0.f, dep = 0.f;
    #pragma unroll
    for (int i = 0; i < 8; ++i) {
        cr  += w[i] * col[3 * i + 0];
        cg  += w[i] * col[3 * i + 1];
        cb  += w[i] * col[3 * i + 2];
        dep += w[i] * z[i];                      // unscaled z
    }

    // ---- segmented reductions (totals at sl==15) ----
    cr    = scan_add16(cr);
    cg    = scan_add16(cg);
    cb    = scan_add16(cb);
    dep   = scan_add16(dep);
    ldist = scan_add16(ldist);
    tv    = scan_add16(tv);

    // ---- stores ----
    *reinterpret_cast<float4*>(o_weights + base)     = make_float4(w[0], w[1], w[2], w[3]);
    *reinterpret_cast<float4*>(o_weights + base + 4) = make_float4(w[4], w[5], w[6], w[7]);

    if (sl == 15) {
        o_rgb_map[ray * 3 + 0] = cr + bg_lambda * bgr;
        o_rgb_map[ray * 3 + 1] = cg + bg_lambda * bgg;
        o_rgb_map[ray * 3 + 2] = cb + bg_lambda * bgb;
        o_fg_rgb[ray * 3 + 0] = cr;
        o_fg_rgb[ray * 3 + 1] = cg;
        o_fg_rgb[ray * 3 + 2] = cb;
        o_depth[ray]     = dep;
        o_bg_lambda[ray] = bg_lambda;
        o_ldist[ray]     = ldist;
        o_tv[ray]        = tv;
    }
}

extern "C" void kernel_launch(void* const* d_in, const int* in_sizes, int n_in,
                              void* d_out, int out_size, void* d_ws, size_t ws_size,
                              hipStream_t stream) {
    const float* ray_d   = (const float*)d_in[0];
    const float* fg_zmax = (const float*)d_in[1];
    const float* z_vals  = (const float*)d_in[2];
    const float* sigma   = (const float*)d_in[3];
    const float* rgb     = (const float*)d_in[4];
    const float* bg_rgb  = (const float*)d_in[5];

    const int R = in_sizes[1];          // fg_z_max: [R]

    float* out = (float*)d_out;
    float* o_rgb_map   = out;                       // R*3
    float* o_weights   = o_rgb_map + (long)R * 3;   // R*128
    float* o_fg_rgb    = o_weights + (long)R * 128; // R*3
    float* o_depth     = o_fg_rgb + (long)R * 3;    // R
    float* o_bg_lambda = o_depth + R;               // R
    float* o_ldist     = o_bg_lambda + R;           // R
    float* o_tv        = o_ldist + R;               // R

    // 4 rays per wave, 4 waves per block -> 16 rays per block
    const int rays_per_block = 16;
    const int grid = (R + rays_per_block - 1) / rays_per_block;
    nerf_render_kernel<<<grid, 256, 0, stream>>>(
        ray_d, fg_zmax, z_vals, sigma, rgb, bg_rgb,
        o_rgb_map, o_weights, o_fg_rgb, o_depth, o_bg_lambda, o_ldist, o_tv, R);
}